// Round 4
// baseline (758.559 us; speedup 1.0000x reference)
//
#include <hip/hip_runtime.h>
#include <hip/hip_bf16.h>

#define B 32
#define A 32768
#define G 64
#define C 91
#define NBINS 2048

typedef unsigned long long ull;

// ---------------- workspace layout (bytes) ----------------
static constexpr size_t offMatched = 0;                     // B*A*4
static constexpr size_t offBits    = (size_t)B * A * 4;     // packed loss bits
static constexpr size_t offNumFg   = (size_t)2 * B * A * 4; // B*4
static constexpr size_t offAcc     = offNumFg + B * 4;      // 3 doubles
static constexpr size_t offTick    = offAcc + 3 * 8;        // 2 ints
static constexpr size_t offGt      = offTick + 8;           // B*G ull (8-aligned)
static constexpr int    ZERO_N     = (int)((offGt - offNumFg) / 4);  // 40

// ---------------- init ----------------
__global__ void init_kernel(int* zero_base, ull* gtpack) {
  int i = blockIdx.x * 256 + threadIdx.x;
  if (i < ZERO_N) zero_base[i] = 0;
  if (i < B * G) gtpack[i] = 0xFFFFFFFFull;
}

// ---------------- match ----------------
// 4 anchors per thread (stride 256 within a 1024-anchor block): one GT
// broadcast LDS read amortizes over 4 IOUs; loop overhead /4; the 4 packed
// candidates fold into one pmax before the filtered LDS atomic. Exact f32
// division + ascending-g compare order kept -> bit-identical matched/gtpack.
// NOTE (round-2 post-mortem): force stays a separate dispatch — an in-kernel
// device fence across all blocks cost ~280 us of L2 writeback.
#define MAPB 1024
__global__ __launch_bounds__(256) void match_kernel(
    const float4* __restrict__ anchors, const float4* __restrict__ gt_boxes,
    int* __restrict__ matched, ull* __restrict__ gtpack) {
#pragma clang fp contract(off)
  int b = blockIdx.y;
  int a0 = blockIdx.x * MAPB + threadIdx.x;
  size_t abase = (size_t)b * A;
  __shared__ float4 gtb[G];
  __shared__ float gtarea[G];
  __shared__ ull best[G];
  if (threadIdx.x < G) {
    float4 g = gt_boxes[b * G + threadIdx.x];
    gtb[threadIdx.x] = g;
    gtarea[threadIdx.x] = (g.z - g.x) * (g.w - g.y);
    best[threadIdx.x] = 0ull;
  }
  __syncthreads();
  float4 an[4];
  float area_a[4];
  float bestv[4];
  int bestg[4];
#pragma unroll
  for (int k = 0; k < 4; ++k) {
    an[k] = anchors[abase + a0 + k * 256];
    area_a[k] = (an[k].z - an[k].x) * (an[k].w - an[k].y);
    bestv[k] = -1.0f;
    bestg[k] = 0;
  }
  for (int g = 0; g < G; ++g) {
    float4 gb = gtb[g];
    float ga = gtarea[g];
    ull pmax = 0ull;
#pragma unroll
    for (int k = 0; k < 4; ++k) {
      float tlx = fmaxf(gb.x, an[k].x), tly = fmaxf(gb.y, an[k].y);
      float brx = fminf(gb.z, an[k].z), bry = fminf(gb.w, an[k].w);
      float w = fmaxf(brx - tlx, 0.0f), h = fmaxf(bry - tly, 0.0f);
      float inter = w * h;
      if (inter > 0.0f) {
        float iou = inter / (ga + area_a[k] - inter + 1e-16f);
        if (iou > bestv[k]) { bestv[k] = iou; bestg[k] = g; }
        ull p = ((ull)__float_as_uint(iou) << 32) | (unsigned)(~(unsigned)(a0 + k * 256));
        if (p > pmax) pmax = p;
      }
    }
    if (pmax > best[g]) atomicMax(&best[g], pmax);
  }
#pragma unroll
  for (int k = 0; k < 4; ++k)
    matched[abase + a0 + k * 256] = (bestv[k] < 0.45f) ? -1 : bestg[k];
  __syncthreads();
  if (threadIdx.x < G) {
    ull p = best[threadIdx.x];
    if (p) atomicMax(&gtpack[b * G + threadIdx.x], p);
  }
}

// ---------------- force match (separate dispatch = free coherence) ----------------
__global__ void force_kernel(const ull* __restrict__ gtpack, int* __restrict__ matched) {
  int b = blockIdx.x * blockDim.x + threadIdx.x;
  if (b < B) {
    for (int g = 0; g < G; ++g) {   // ascending g: last-wins tie order
      unsigned a = ~(unsigned)(gtpack[b * G + g] & 0xFFFFFFFFull);
      matched[(size_t)b * A + a] = g;
    }
  }
}

// ---------------- fused softmax + decode + giou ----------------
// 8 threads per anchor (was 4): APB=32, NT=16. LDS per block halves to
// 2 x 11.6 KB -> 6 blocks/CU = 24 waves/CU (was 12), attacking the latency-
// bound regime (occupancy was 29.7%, BW only ~3 TB/s). Staging still via
// __builtin_amdgcn_global_load_lds width=16 (no VGPR/scratch round trip).
// Classes split 12/12/12/11*5 across q=0..7; three shfl_xor join.
#define APB 32
#define NT 16
#define NF4 (APB * C / 4)               // 728 float4 per tile
#define NSTG 3                          // ceil(728/256)
#define TAILN (NF4 - (NSTG - 1) * 256)  // 216

__device__ __forceinline__ void stage_tile(const float4* src, float* dst, int tid) {
  int wbase = tid & ~63;  // wave-uniform LDS base; HW adds lane*16
#pragma unroll
  for (int r = 0; r < NSTG - 1; ++r)
    __builtin_amdgcn_global_load_lds(
        (const __attribute__((address_space(1))) void*)(src + r * 256 + tid),
        (__attribute__((address_space(3))) void*)(dst + (r * 256 + wbase) * 4),
        16, 0, 0);
  if (tid < TAILN)
    __builtin_amdgcn_global_load_lds(
        (const __attribute__((address_space(1))) void*)(src + (NSTG - 1) * 256 + tid),
        (__attribute__((address_space(3))) void*)(dst + ((NSTG - 1) * 256 + wbase) * 4),
        16, 0, 0);
}

__global__ __launch_bounds__(256, 6) void loss_kernel(
    const float4* __restrict__ logit4, const float4* __restrict__ reg,
    const float4* __restrict__ anchors, const float4* __restrict__ gt_boxes,
    const int* __restrict__ gt_labels, const int* __restrict__ matched,
    unsigned* __restrict__ cls_bits, int* __restrict__ num_fg, double* __restrict__ acc) {
  __shared__ float buf[2][APB * C];  // 2 x 11648 B
  __shared__ double rb[4], rf[4];
  __shared__ int rc[4];
  int tid = threadIdx.x;
  int b = blockIdx.y;
  int tile0 = blockIdx.x * NT;
  size_t bbase4 = (size_t)b * A * C / 4;
  int t8 = tid >> 3, q = tid & 7;
  const int off = q * 11 + (q < 3 ? q : 3);   // 0,12,24,36,47,58,69,80
  const int cn = 11 + (q < 3 ? 1 : 0);        // 12,12,12,11,11,11,11,11

  stage_tile(logit4 + bbase4 + (size_t)tile0 * NF4, buf[0], tid);
  int mmCur = matched[(size_t)b * A + tile0 * APB + t8];
  int tclsCur = (mmCur >= 0) ? gt_labels[b * G + mmCur] : (C - 1);
  __syncthreads();  // drains vmcnt(0) -> buf[0] ready

  double bbs = 0.0, fgs = 0.0;
  int cnt = 0;

  for (int t = 0; t < NT; ++t) {
    int cur = t & 1;
    if (t + 1 < NT)
      stage_tile(logit4 + bbase4 + (size_t)(tile0 + t + 1) * NF4, buf[cur ^ 1], tid);
    int mmNext = 0, tclsNext = 0;
    if (t + 1 < NT) {
      mmNext = matched[(size_t)b * A + (tile0 + t + 1) * APB + t8];
      tclsNext = (mmNext >= 0) ? gt_labels[b * G + mmNext] : (C - 1);
    }
    {
      const float* BC = buf[cur];
      int a = (tile0 + t) * APB + t8;
      const float* row = BC + t8 * C + off;
      float s0 = 0.f, s1 = 0.f, s2 = 0.f, s3 = 0.f;
#pragma unroll
      for (int j = 0; j < 8; j += 4) {
        s0 += __expf(row[j]);
        s1 += __expf(row[j + 1]);
        s2 += __expf(row[j + 2]);
        s3 += __expf(row[j + 3]);
      }
      for (int j = 8; j < cn; ++j) s0 += __expf(row[j]);
      float s = (s0 + s1) + (s2 + s3);
      s += __shfl_xor(s, 1);
      s += __shfl_xor(s, 2);
      s += __shfl_xor(s, 4);
      float lse = __logf(s);
      float xt = BC[t8 * C + tclsCur];
      float loss = lse - xt;
      if (q == 0) {
        cls_bits[(size_t)b * A + a] = (mmCur >= 0) ? 0u : __float_as_uint(loss);
        if (mmCur >= 0) {
          fgs += (double)loss;
          cnt++;
          float4 an = anchors[(size_t)b * A + a];
          float4 rg = reg[(size_t)b * A + a];
          float4 gb = gt_boxes[b * G + mmCur];
          float w = an.z - an.x, h = an.w - an.y;
          float cx = an.x + 0.5f * w, cy = an.y + 0.5f * h;
          float dw = fminf(rg.z, 4.135166556742356f);
          float dh = fminf(rg.w, 4.135166556742356f);
          float pcx = rg.x * w + cx, pcy = rg.y * h + cy;
          float pw = expf(dw) * w, ph = expf(dh) * h;
          float px0 = pcx - 0.5f * pw, py0 = pcy - 0.5f * ph;
          float px1 = pcx + 0.5f * pw, py1 = pcy + 0.5f * ph;
          float tlx = fmaxf(px0, gb.x), tly = fmaxf(py0, gb.y);
          float brx = fminf(px1, gb.z), bry = fminf(py1, gb.w);
          float iw = fmaxf(brx - tlx, 0.f), ih = fmaxf(bry - tly, 0.f);
          float inter = iw * ih;
          float ap = (px1 - px0) * (py1 - py0);
          float ag = (gb.z - gb.x) * (gb.w - gb.y);
          float uni = ap + ag - inter + 1e-16f;
          float iou = inter / uni;
          float ctlx = fminf(px0, gb.x), ctly = fminf(py0, gb.y);
          float cbrx = fmaxf(px1, gb.z), cbry = fmaxf(py1, gb.w);
          float acr = (cbrx - ctlx) * (cbry - ctly);
          float giou = iou - (acr - uni) / fmaxf(acr, 1e-16f);
          giou = fminf(fmaxf(giou, -1.f), 1.f);
          bbs += (double)(1.f - giou);
        }
      }
    }
    mmCur = mmNext;
    tclsCur = tclsNext;
    __syncthreads();  // buf[cur] free to re-stage; vmcnt(0) drain readies other buf
  }

  int lane = tid & 63, wave = tid >> 6;
  for (int o = 32; o; o >>= 1) {
    bbs += __shfl_xor(bbs, o);
    fgs += __shfl_xor(fgs, o);
    cnt += __shfl_xor(cnt, o);
  }
  if (lane == 0) { rb[wave] = bbs; rf[wave] = fgs; rc[wave] = cnt; }
  __syncthreads();
  if (tid == 0) {
    double tb = rb[0] + rb[1] + rb[2] + rb[3];
    double tf = rf[0] + rf[1] + rf[2] + rf[3];
    int tc = rc[0] + rc[1] + rc[2] + rc[3];
    if (tb != 0.0) atomicAdd(&acc[0], tb);
    if (tf != 0.0) atomicAdd(&acc[1], tf);
    if (tc) atomicAdd(&num_fg[b], tc);
  }
}

// ---------------- fused 3-level radix select + bgsum + finalize ----------------
// One block per image b, 1024 threads. Each thread register-caches its 32
// packed loss words (fg anchors carry sentinel 0u = +0.0f: sentinel sits in
// bin 0 / value 0.0, which can only influence the result when T==0.0, where
// its r*T and v>T contributions are both exactly 0 -> bit-exact vs separate
// matched test). All histograms live in LDS; selection logic is verbatim
// the original select_kernel. Last block (device ticket) finalizes out[].
// The ticket here is cheap: only B=32 blocks pay the fence, not 4096.
__global__ __launch_bounds__(1024) void select_fused(
    const unsigned* __restrict__ bits, const int* __restrict__ num_fg,
    double* __restrict__ acc, int* __restrict__ ticket, float* __restrict__ out) {
  int b = blockIdx.x, tid = threadIdx.x;
  __shared__ int h[NBINS];
  __shared__ int gsum[256];
  __shared__ float sT;
  __shared__ int sDone, sKrem, sR;
  __shared__ unsigned sPref;
  __shared__ double sd[16];

  unsigned bv[32];
#pragma unroll
  for (int i = 0; i < 32; ++i) bv[i] = bits[(size_t)b * A + i * 1024 + tid];
  if (tid == 0) { sDone = 0; sR = 0; }

  // ---- level 1 ----
  for (int i = tid; i < NBINS; i += 1024) h[i] = 0;
  __syncthreads();
#pragma unroll
  for (int i = 0; i < 32; ++i) atomicAdd(&h[bv[i] >> 21], 1);
  __syncthreads();
  if (tid < 256) {
    int gs = 0;
#pragma unroll
    for (int j = 0; j < 8; ++j) gs += h[tid * 8 + j];
    gsum[tid] = gs;
  }
  __syncthreads();
  if (tid == 0) {
    int nf = num_fg[b];
    int k = 3 * nf;
    int bgcnt = A - nf;
    if (k <= 0) { sT = __builtin_inff(); sDone = 1; }
    else if (k >= bgcnt) { sT = -1.0f; sDone = 1; }
    else {
      int run = 0, gidx = 255;
      for (; gidx >= 0; --gidx) { if (run + gsum[gidx] >= k) break; run += gsum[gidx]; }
      if (gidx < 0) { sT = -1.0f; sDone = 1; }
      else {
        int bin = gidx * 8 + 7;
        for (; bin > gidx * 8; --bin) { if (run + h[bin] >= k) break; run += h[bin]; }
        sPref = (unsigned)bin; sKrem = k - run;
      }
    }
  }
  __syncthreads();

  if (!sDone) {  // block-uniform branch
    // ---- level 2 ----
    unsigned p1 = sPref;
    int k = sKrem;
    __syncthreads();
    for (int i = tid; i < NBINS; i += 1024) h[i] = 0;
    __syncthreads();
#pragma unroll
    for (int i = 0; i < 32; ++i)
      if ((bv[i] >> 21) == p1) atomicAdd(&h[(bv[i] >> 10) & 2047], 1);
    __syncthreads();
    if (tid < 256) {
      int gs = 0;
#pragma unroll
      for (int j = 0; j < 8; ++j) gs += h[tid * 8 + j];
      gsum[tid] = gs;
    }
    __syncthreads();
    if (tid == 0) {
      int run = 0, gidx = 255;
      for (; gidx >= 0; --gidx) { if (run + gsum[gidx] >= k) break; run += gsum[gidx]; }
      if (gidx < 0) { sT = -1.0f; sDone = 1; }
      else {
        int bin = gidx * 8 + 7;
        for (; bin > gidx * 8; --bin) { if (run + h[bin] >= k) break; run += h[bin]; }
        sPref = (p1 << 11) | (unsigned)bin; sKrem = k - run;
      }
    }
    __syncthreads();
  }
  if (!sDone) {
    // ---- level 3 ----
    unsigned p2 = sPref;
    int k = sKrem;
    __syncthreads();
    if (tid < 1024) h[tid] = 0;
    __syncthreads();
#pragma unroll
    for (int i = 0; i < 32; ++i)
      if ((bv[i] >> 10) == p2) atomicAdd(&h[bv[i] & 1023], 1);
    __syncthreads();
    if (tid < 256) {
      int gs = 0;
#pragma unroll
      for (int j = 0; j < 4; ++j) gs += h[tid * 4 + j];
      gsum[tid] = gs;
    }
    __syncthreads();
    if (tid == 0) {
      int run = 0, gidx = 255;
      for (; gidx >= 0; --gidx) { if (run + gsum[gidx] >= k) break; run += gsum[gidx]; }
      if (gidx < 0) { sT = -1.0f; }
      else {
        int bin = gidx * 4 + 3;
        for (; bin > gidx * 4; --bin) { if (run + h[bin] >= k) break; run += h[bin]; }
        sT = __uint_as_float((p2 << 10) | (unsigned)bin);
        sR = k - run;
      }
    }
    __syncthreads();
  }

  // ---- bg sum over threshold (+ r*T) ----
  float T = sT;
  float ls = 0.f;
#pragma unroll
  for (int i = 0; i < 32; ++i) {
    float v = __uint_as_float(bv[i]);
    if (v > T) ls += v;   // sentinel 0.0 adds exactly 0 when T<0
  }
  for (int o = 32; o; o >>= 1) ls += __shfl_xor(ls, o);
  if ((tid & 63) == 0) sd[tid >> 6] = (double)ls;
  __syncthreads();
  if (tid == 0) {
    double tt = 0.0;
    for (int w = 0; w < 16; ++w) tt += sd[w];
    if (sR > 0) tt += (double)sR * (double)sT;
    if (tt != 0.0) atomicAdd(&acc[2], tt);
    __threadfence();
    if (atomicAdd(ticket, 1) == B - 1) {
      // last block: finalize. acc[0..1]/num_fg written in a previous
      // dispatch (visible); acc[2] written by sibling blocks -> atomic read.
      int tot = 0;
      for (int bb = 0; bb < B; ++bb) tot += num_fg[bb];
      double N = (double)(tot > 1 ? tot : 1);
      double a2 = atomicAdd(&acc[2], 0.0);
      out[0] = (float)(2.0 * acc[0] / N);
      out[1] = (float)((acc[1] + a2) / N);
    }
  }
}

extern "C" void kernel_launch(void* const* d_in, const int* in_sizes, int n_in,
                              void* d_out, int out_size, void* d_ws, size_t ws_size,
                              hipStream_t stream) {
  const float4* logit4  = (const float4*)d_in[0];
  const float4* reg     = (const float4*)d_in[1];
  const float4* anchors = (const float4*)d_in[2];
  const float4* gtb     = (const float4*)d_in[3];
  const int*    gtl     = (const int*)d_in[4];

  char* ws = (char*)d_ws;
  int*      matched = (int*)(ws + offMatched);
  unsigned* cbits   = (unsigned*)(ws + offBits);
  int*      numfg   = (int*)(ws + offNumFg);
  double*   acc     = (double*)(ws + offAcc);
  int*      tick    = (int*)(ws + offTick);
  ull*      gtpack  = (ull*)(ws + offGt);
  float*    out     = (float*)d_out;

  init_kernel<<<8, 256, 0, stream>>>((int*)(ws + offNumFg), gtpack);
  match_kernel<<<dim3(A / MAPB, B), 256, 0, stream>>>(anchors, gtb, matched, gtpack);
  force_kernel<<<1, 64, 0, stream>>>(gtpack, matched);
  loss_kernel<<<dim3(A / (APB * NT), B), 256, 0, stream>>>(
      logit4, reg, anchors, gtb, gtl, matched, cbits, numfg, acc);
  select_fused<<<B, 1024, 0, stream>>>(cbits, numfg, acc, tick + 1, out);
}

// Round 5
// 710.558 us; speedup vs baseline: 1.0676x; 1.0676x over previous
//
#include <hip/hip_runtime.h>
#include <hip/hip_bf16.h>

#define B 32
#define A 32768
#define G 64
#define C 91
#define NBINS 2048

typedef unsigned long long ull;

// ---------------- workspace layout (bytes) ----------------
static constexpr size_t offMatched = 0;                     // B*A*4
static constexpr size_t offBits    = (size_t)B * A * 4;     // packed loss bits
static constexpr size_t offNumFg   = (size_t)2 * B * A * 4; // B*4
static constexpr size_t offAcc     = offNumFg + B * 4;      // 3 doubles
static constexpr size_t offTick    = offAcc + 3 * 8;        // 2 ints
static constexpr size_t offGt      = offTick + 8;           // B*G ull (8-aligned)
static constexpr int    ZERO_N     = (int)((offGt - offNumFg) / 4);  // 40

// ---------------- init ----------------
__global__ void init_kernel(int* zero_base, ull* gtpack) {
  int i = blockIdx.x * 256 + threadIdx.x;
  if (i < ZERO_N) zero_base[i] = 0;
  if (i < B * G) gtpack[i] = 0xFFFFFFFFull;
}

// ---------------- match ----------------
// Round-3 proven version (1 anchor/thread, full 16384-wave grid for TLP).
// Round-4 post-mortem: 4-anchors/thread shrank the grid 4x -> 16 waves/CU
// demand and likely regressed; reverted.
// NOTE (round-2 post-mortem): force stays a separate dispatch — an in-kernel
// device fence across all blocks cost ~280 us of L2 writeback.
__global__ __launch_bounds__(256) void match_kernel(
    const float4* __restrict__ anchors, const float4* __restrict__ gt_boxes,
    int* __restrict__ matched, ull* __restrict__ gtpack) {
#pragma clang fp contract(off)
  int b = blockIdx.y;
  int a = blockIdx.x * 256 + threadIdx.x;
  __shared__ float4 gtb[G];
  __shared__ float gtarea[G];
  __shared__ ull best[G];
  if (threadIdx.x < G) {
    float4 g = gt_boxes[b * G + threadIdx.x];
    gtb[threadIdx.x] = g;
    gtarea[threadIdx.x] = (g.z - g.x) * (g.w - g.y);
    best[threadIdx.x] = 0ull;
  }
  __syncthreads();
  float4 an = anchors[(size_t)b * A + a];
  float area_a = (an.z - an.x) * (an.w - an.y);
  float bestv = -1.0f;
  int bestg = 0;
  for (int g = 0; g < G; ++g) {
    float4 gb = gtb[g];
    float tlx = fmaxf(gb.x, an.x), tly = fmaxf(gb.y, an.y);
    float brx = fminf(gb.z, an.z), bry = fminf(gb.w, an.w);
    float w = fmaxf(brx - tlx, 0.0f), h = fmaxf(bry - tly, 0.0f);
    float inter = w * h;
    float iou = 0.0f;
    if (inter > 0.0f) iou = inter / (gtarea[g] + area_a - inter + 1e-16f);
    if (iou > bestv) { bestv = iou; bestg = g; }
    if (iou > 0.0f) {
      ull p = ((ull)__float_as_uint(iou) << 32) | (unsigned)(~(unsigned)a);
      if (p > best[g]) atomicMax(&best[g], p);
    }
  }
  matched[(size_t)b * A + a] = (bestv < 0.45f) ? -1 : bestg;
  __syncthreads();
  if (threadIdx.x < G) {
    ull p = best[threadIdx.x];
    if (p) atomicMax(&gtpack[b * G + threadIdx.x], p);
  }
}

// ---------------- force match (separate dispatch = free coherence) ----------------
__global__ void force_kernel(const ull* __restrict__ gtpack, int* __restrict__ matched) {
  int b = blockIdx.x * blockDim.x + threadIdx.x;
  if (b < B) {
    for (int g = 0; g < G; ++g) {   // ascending g: last-wins tie order
      unsigned a = ~(unsigned)(gtpack[b * G + g] & 0xFFFFFFFFull);
      matched[(size_t)b * A + a] = g;
    }
  }
}

// ---------------- fused softmax + decode + giou (counted-vmcnt pipeline) ----------------
// APB=64/NT=8 geometry (round-3 proven), but the per-tile barrier no longer
// drains vmcnt(0): raw s_barrier + s_waitcnt vmcnt(5). stage(t+1)'s >=5
// per-wave DMA loads are always the newest VMEM ops at the top of iter t, so
// vmcnt(5) (in-order retirement, all-but-newest-5 complete) guarantees tile t
// is fully in LDS regardless of interleaved cls_bits stores / fg loads.
// The DMA queue therefore never empties (was: full drain per tile = exposed
// HBM latency x8). Metadata (matched/labels) hoisted to a fully-unrolled
// register prologue so compiler waits for it can't drain the pipe.
#define APB 64
#define NT 8
#define NF4 (APB * C / 4)               // 1456 float4 per tile
#define NSTG 6                          // ceil(1456/256)
#define TAILN (NF4 - (NSTG - 1) * 256)  // 176

__device__ __forceinline__ void stage_tile(const float4* src, float* dst, int tid) {
  int wbase = tid & ~63;  // wave-uniform LDS base; HW adds lane*16
#pragma unroll
  for (int r = 0; r < NSTG - 1; ++r)
    __builtin_amdgcn_global_load_lds(
        (const __attribute__((address_space(1))) void*)(src + r * 256 + tid),
        (__attribute__((address_space(3))) void*)(dst + (r * 256 + wbase) * 4),
        16, 0, 0);
  if (tid < TAILN)   // waves issue {6,6,6,5} loads -> vmcnt(5) is the safe count
    __builtin_amdgcn_global_load_lds(
        (const __attribute__((address_space(1))) void*)(src + (NSTG - 1) * 256 + tid),
        (__attribute__((address_space(3))) void*)(dst + ((NSTG - 1) * 256 + wbase) * 4),
        16, 0, 0);
}

__global__ __launch_bounds__(256) void loss_kernel(
    const float4* __restrict__ logit4, const float4* __restrict__ reg,
    const float4* __restrict__ anchors, const float4* __restrict__ gt_boxes,
    const int* __restrict__ gt_labels, const int* __restrict__ matched,
    unsigned* __restrict__ cls_bits, int* __restrict__ num_fg, double* __restrict__ acc) {
  __shared__ float buf[2][APB * C];  // 2 x 23296 B -> 3 blocks/CU
  __shared__ double rb[4], rf[4];
  __shared__ int rc[4];
  int tid = threadIdx.x;
  int b = blockIdx.y;
  int tile0 = blockIdx.x * NT;
  size_t bbase4 = (size_t)b * A * C / 4;
  int t4 = tid >> 2, q = tid & 3;

  // ---- metadata prologue (before any DMA, so its waits are free) ----
  int mm[NT], tcls[NT];
#pragma unroll
  for (int t = 0; t < NT; ++t) {
    mm[t] = matched[(size_t)b * A + (tile0 + t) * APB + t4];
    tcls[t] = (mm[t] >= 0) ? gt_labels[b * G + mm[t]] : (C - 1);
  }

  // ---- prime the pipeline: 2 tiles in flight ----
  stage_tile(logit4 + bbase4 + (size_t)tile0 * NF4, buf[0], tid);
  stage_tile(logit4 + bbase4 + (size_t)(tile0 + 1) * NF4, buf[1], tid);

  double bbs = 0.0, fgs = 0.0;
  int cnt = 0;

#pragma unroll
  for (int t = 0; t < NT; ++t) {
    // wait: tile t's loads complete; stage(t+1)'s >=5 stay in flight
    if (t < NT - 1) {
      asm volatile("s_waitcnt vmcnt(5)" ::: "memory");
    } else {
      asm volatile("s_waitcnt vmcnt(0)" ::: "memory");
    }
    __builtin_amdgcn_s_barrier();          // all waves' tile-t chunks landed
    __builtin_amdgcn_sched_barrier(0);
    {
      const float* BC = buf[t & 1];
      int a = (tile0 + t) * APB + t4;
      const float* row = BC + t4 * C + 23 * q;
      const int cn = (q < 3) ? 23 : 22;
      float s0 = 0.f, s1 = 0.f, s2 = 0.f, s3 = 0.f;
      int j = 0;
#pragma unroll
      for (; j + 4 <= 20; j += 4) {
        s0 += __expf(row[j]);
        s1 += __expf(row[j + 1]);
        s2 += __expf(row[j + 2]);
        s3 += __expf(row[j + 3]);
      }
      for (; j < cn; ++j) s0 += __expf(row[j]);
      float s = (s0 + s1) + (s2 + s3);
      s += __shfl_xor(s, 1);
      s += __shfl_xor(s, 2);
      float lse = __logf(s);
      float xt = BC[t4 * C + tcls[t]];
      float loss = lse - xt;
      if (q == 0) {
        cls_bits[(size_t)b * A + a] = (mm[t] >= 0) ? 0u : __float_as_uint(loss);
        if (mm[t] >= 0) {
          fgs += (double)loss;
          cnt++;
          float4 an = anchors[(size_t)b * A + a];
          float4 rg = reg[(size_t)b * A + a];
          float4 gb = gt_boxes[b * G + mm[t]];
          float w = an.z - an.x, h = an.w - an.y;
          float cx = an.x + 0.5f * w, cy = an.y + 0.5f * h;
          float dw = fminf(rg.z, 4.135166556742356f);
          float dh = fminf(rg.w, 4.135166556742356f);
          float pcx = rg.x * w + cx, pcy = rg.y * h + cy;
          float pw = expf(dw) * w, ph = expf(dh) * h;
          float px0 = pcx - 0.5f * pw, py0 = pcy - 0.5f * ph;
          float px1 = pcx + 0.5f * pw, py1 = pcy + 0.5f * ph;
          float tlx = fmaxf(px0, gb.x), tly = fmaxf(py0, gb.y);
          float brx = fminf(px1, gb.z), bry = fminf(py1, gb.w);
          float iw = fmaxf(brx - tlx, 0.f), ih = fmaxf(bry - tly, 0.f);
          float inter = iw * ih;
          float ap = (px1 - px0) * (py1 - py0);
          float ag = (gb.z - gb.x) * (gb.w - gb.y);
          float uni = ap + ag - inter + 1e-16f;
          float iou = inter / uni;
          float ctlx = fminf(px0, gb.x), ctly = fminf(py0, gb.y);
          float cbrx = fmaxf(px1, gb.z), cbry = fmaxf(py1, gb.w);
          float acr = (cbrx - ctlx) * (cbry - ctly);
          float giou = iou - (acr - uni) / fmaxf(acr, 1e-16f);
          giou = fminf(fmaxf(giou, -1.f), 1.f);
          bbs += (double)(1.f - giou);
        }
      }
    }
    __builtin_amdgcn_s_barrier();          // all waves done reading buf[t&1]
    __builtin_amdgcn_sched_barrier(0);
    if (t + 2 < NT)                        // refill the buffer just freed
      stage_tile(logit4 + bbase4 + (size_t)(tile0 + t + 2) * NF4, buf[t & 1], tid);
  }

  int lane = tid & 63, wave = tid >> 6;
  for (int o = 32; o; o >>= 1) {
    bbs += __shfl_xor(bbs, o);
    fgs += __shfl_xor(fgs, o);
    cnt += __shfl_xor(cnt, o);
  }
  if (lane == 0) { rb[wave] = bbs; rf[wave] = fgs; rc[wave] = cnt; }
  __syncthreads();
  if (tid == 0) {
    double tb = rb[0] + rb[1] + rb[2] + rb[3];
    double tf = rf[0] + rf[1] + rf[2] + rf[3];
    int tc = rc[0] + rc[1] + rc[2] + rc[3];
    if (tb != 0.0) atomicAdd(&acc[0], tb);
    if (tf != 0.0) atomicAdd(&acc[1], tf);
    if (tc) atomicAdd(&num_fg[b], tc);
  }
}

// ---------------- fused 3-level radix select + bgsum + finalize ----------------
// One block per image b, 1024 threads. Each thread register-caches its 32
// packed loss words (fg anchors carry sentinel 0u = +0.0f: sentinel sits in
// bin 0 / value 0.0, which can only influence the result when T==0.0, where
// its r*T and v>T contributions are both exactly 0 -> bit-exact vs separate
// matched test). All histograms live in LDS; selection logic is verbatim
// the original select_kernel. Last block (device ticket) finalizes out[].
// The ticket here is cheap: only B=32 blocks pay the fence, not 4096.
__global__ __launch_bounds__(1024) void select_fused(
    const unsigned* __restrict__ bits, const int* __restrict__ num_fg,
    double* __restrict__ acc, int* __restrict__ ticket, float* __restrict__ out) {
  int b = blockIdx.x, tid = threadIdx.x;
  __shared__ int h[NBINS];
  __shared__ int gsum[256];
  __shared__ float sT;
  __shared__ int sDone, sKrem, sR;
  __shared__ unsigned sPref;
  __shared__ double sd[16];

  unsigned bv[32];
#pragma unroll
  for (int i = 0; i < 32; ++i) bv[i] = bits[(size_t)b * A + i * 1024 + tid];
  if (tid == 0) { sDone = 0; sR = 0; }

  // ---- level 1 ----
  for (int i = tid; i < NBINS; i += 1024) h[i] = 0;
  __syncthreads();
#pragma unroll
  for (int i = 0; i < 32; ++i) atomicAdd(&h[bv[i] >> 21], 1);
  __syncthreads();
  if (tid < 256) {
    int gs = 0;
#pragma unroll
    for (int j = 0; j < 8; ++j) gs += h[tid * 8 + j];
    gsum[tid] = gs;
  }
  __syncthreads();
  if (tid == 0) {
    int nf = num_fg[b];
    int k = 3 * nf;
    int bgcnt = A - nf;
    if (k <= 0) { sT = __builtin_inff(); sDone = 1; }
    else if (k >= bgcnt) { sT = -1.0f; sDone = 1; }
    else {
      int run = 0, gidx = 255;
      for (; gidx >= 0; --gidx) { if (run + gsum[gidx] >= k) break; run += gsum[gidx]; }
      if (gidx < 0) { sT = -1.0f; sDone = 1; }
      else {
        int bin = gidx * 8 + 7;
        for (; bin > gidx * 8; --bin) { if (run + h[bin] >= k) break; run += h[bin]; }
        sPref = (unsigned)bin; sKrem = k - run;
      }
    }
  }
  __syncthreads();

  if (!sDone) {  // block-uniform branch
    // ---- level 2 ----
    unsigned p1 = sPref;
    int k = sKrem;
    __syncthreads();
    for (int i = tid; i < NBINS; i += 1024) h[i] = 0;
    __syncthreads();
#pragma unroll
    for (int i = 0; i < 32; ++i)
      if ((bv[i] >> 21) == p1) atomicAdd(&h[(bv[i] >> 10) & 2047], 1);
    __syncthreads();
    if (tid < 256) {
      int gs = 0;
#pragma unroll
      for (int j = 0; j < 8; ++j) gs += h[tid * 8 + j];
      gsum[tid] = gs;
    }
    __syncthreads();
    if (tid == 0) {
      int run = 0, gidx = 255;
      for (; gidx >= 0; --gidx) { if (run + gsum[gidx] >= k) break; run += gsum[gidx]; }
      if (gidx < 0) { sT = -1.0f; sDone = 1; }
      else {
        int bin = gidx * 8 + 7;
        for (; bin > gidx * 8; --bin) { if (run + h[bin] >= k) break; run += h[bin]; }
        sPref = (p1 << 11) | (unsigned)bin; sKrem = k - run;
      }
    }
    __syncthreads();
  }
  if (!sDone) {
    // ---- level 3 ----
    unsigned p2 = sPref;
    int k = sKrem;
    __syncthreads();
    if (tid < 1024) h[tid] = 0;
    __syncthreads();
#pragma unroll
    for (int i = 0; i < 32; ++i)
      if ((bv[i] >> 10) == p2) atomicAdd(&h[bv[i] & 1023], 1);
    __syncthreads();
    if (tid < 256) {
      int gs = 0;
#pragma unroll
      for (int j = 0; j < 4; ++j) gs += h[tid * 4 + j];
      gsum[tid] = gs;
    }
    __syncthreads();
    if (tid == 0) {
      int run = 0, gidx = 255;
      for (; gidx >= 0; --gidx) { if (run + gsum[gidx] >= k) break; run += gsum[gidx]; }
      if (gidx < 0) { sT = -1.0f; }
      else {
        int bin = gidx * 4 + 3;
        for (; bin > gidx * 4; --bin) { if (run + h[bin] >= k) break; run += h[bin]; }
        sT = __uint_as_float((p2 << 10) | (unsigned)bin);
        sR = k - run;
      }
    }
    __syncthreads();
  }

  // ---- bg sum over threshold (+ r*T) ----
  float T = sT;
  float ls = 0.f;
#pragma unroll
  for (int i = 0; i < 32; ++i) {
    float v = __uint_as_float(bv[i]);
    if (v > T) ls += v;   // sentinel 0.0 adds exactly 0 when T<0
  }
  for (int o = 32; o; o >>= 1) ls += __shfl_xor(ls, o);
  if ((tid & 63) == 0) sd[tid >> 6] = (double)ls;
  __syncthreads();
  if (tid == 0) {
    double tt = 0.0;
    for (int w = 0; w < 16; ++w) tt += sd[w];
    if (sR > 0) tt += (double)sR * (double)sT;
    if (tt != 0.0) atomicAdd(&acc[2], tt);
    __threadfence();
    if (atomicAdd(ticket, 1) == B - 1) {
      // last block: finalize. acc[0..1]/num_fg written in a previous
      // dispatch (visible); acc[2] written by sibling blocks -> atomic read.
      int tot = 0;
      for (int bb = 0; bb < B; ++bb) tot += num_fg[bb];
      double N = (double)(tot > 1 ? tot : 1);
      double a2 = atomicAdd(&acc[2], 0.0);
      out[0] = (float)(2.0 * acc[0] / N);
      out[1] = (float)((acc[1] + a2) / N);
    }
  }
}

extern "C" void kernel_launch(void* const* d_in, const int* in_sizes, int n_in,
                              void* d_out, int out_size, void* d_ws, size_t ws_size,
                              hipStream_t stream) {
  const float4* logit4  = (const float4*)d_in[0];
  const float4* reg     = (const float4*)d_in[1];
  const float4* anchors = (const float4*)d_in[2];
  const float4* gtb     = (const float4*)d_in[3];
  const int*    gtl     = (const int*)d_in[4];

  char* ws = (char*)d_ws;
  int*      matched = (int*)(ws + offMatched);
  unsigned* cbits   = (unsigned*)(ws + offBits);
  int*      numfg   = (int*)(ws + offNumFg);
  double*   acc     = (double*)(ws + offAcc);
  int*      tick    = (int*)(ws + offTick);
  ull*      gtpack  = (ull*)(ws + offGt);
  float*    out     = (float*)d_out;

  init_kernel<<<8, 256, 0, stream>>>((int*)(ws + offNumFg), gtpack);
  match_kernel<<<dim3(A / 256, B), 256, 0, stream>>>(anchors, gtb, matched, gtpack);
  force_kernel<<<1, 64, 0, stream>>>(gtpack, matched);
  loss_kernel<<<dim3(A / (APB * NT), B), 256, 0, stream>>>(
      logit4, reg, anchors, gtb, gtl, matched, cbits, numfg, acc);
  select_fused<<<B, 1024, 0, stream>>>(cbits, numfg, acc, tick + 1, out);
}

// Round 6
// 705.492 us; speedup vs baseline: 1.0752x; 1.0072x over previous
//
#include <hip/hip_runtime.h>
#include <hip/hip_bf16.h>

#define B 32
#define A 32768
#define G 64
#define C 91
#define NBINS 2048

typedef unsigned long long ull;

// ---------------- workspace layout (bytes) ----------------
static constexpr size_t offMatched = 0;                     // B*A*4
static constexpr size_t offBits    = (size_t)B * A * 4;     // packed loss bits
static constexpr size_t offNumFg   = (size_t)2 * B * A * 4; // B*4
static constexpr size_t offAcc     = offNumFg + B * 4;      // 3 doubles
static constexpr size_t offTick    = offAcc + 3 * 8;        // 2 ints
static constexpr size_t offGt      = offTick + 8;           // B*G ull (8-aligned)
static constexpr int    ZERO_N     = (int)((offGt - offNumFg) / 4);  // 40

// ---------------- init ----------------
__global__ void init_kernel(int* zero_base, ull* gtpack) {
  int i = blockIdx.x * 256 + threadIdx.x;
  if (i < ZERO_N) zero_base[i] = 0;
  if (i < B * G) gtpack[i] = 0xFFFFFFFFull;
}

// ---------------- match ----------------
// Round-6 rewrite for ISSUE ECONOMY (match measured ~140 us, ~123 us
// VALU-busy -> issue-bound). Changes vs round-5, all float math identical:
//  * speculative filter reads only the HI word of best[g] (ds_read_b32
//    broadcast + u32 cmp) instead of full u64 read + 64-bit cmp. Stale
//    reads safe: atomicMax is monotone, stale hi only passes MORE.
//  * u64 pack + atomic moved inside the (rare) filter-pass path; lo=~a
//    hoisted (loop-invariant). Tie resolution still exact via u64 atomicMax.
//  * #pragma unroll 4: 4 independent ds_read_b128 in flight, loop ovh /4.
// NOTE (round-2 post-mortem): force stays a separate dispatch — an in-kernel
// device fence across all blocks cost ~280 us of L2 writeback.
__global__ __launch_bounds__(256) void match_kernel(
    const float4* __restrict__ anchors, const float4* __restrict__ gt_boxes,
    int* __restrict__ matched, ull* __restrict__ gtpack) {
#pragma clang fp contract(off)
  int b = blockIdx.y;
  int a = blockIdx.x * 256 + threadIdx.x;
  __shared__ float4 gtb[G];
  __shared__ float gtarea[G];
  __shared__ ull best[G];
  if (threadIdx.x < G) {
    float4 g = gt_boxes[b * G + threadIdx.x];
    gtb[threadIdx.x] = g;
    gtarea[threadIdx.x] = (g.z - g.x) * (g.w - g.y);
    best[threadIdx.x] = 0ull;
  }
  __syncthreads();
  const unsigned* besthi = (const unsigned*)best;  // little-endian: hi at [2g+1]
  float4 an = anchors[(size_t)b * A + a];
  float area_a = (an.z - an.x) * (an.w - an.y);
  const unsigned lo = ~(unsigned)a;
  float bestv = -1.0f;
  int bestg = 0;
#pragma unroll 4
  for (int g = 0; g < G; ++g) {
    float4 gb = gtb[g];
    float tlx = fmaxf(gb.x, an.x), tly = fmaxf(gb.y, an.y);
    float brx = fminf(gb.z, an.z), bry = fminf(gb.w, an.w);
    float w = fmaxf(brx - tlx, 0.0f), h = fmaxf(bry - tly, 0.0f);
    float inter = w * h;
    if (inter > 0.0f) {
      float iou = inter / (gtarea[g] + area_a - inter + 1e-16f);  // exact, same order
      if (iou > bestv) { bestv = iou; bestg = g; }
      unsigned ib = __float_as_uint(iou);
      if (ib >= besthi[2 * g + 1])        // u32 filter; >= keeps index tiebreak alive
        atomicMax(&best[g], ((ull)ib << 32) | lo);
    }
  }
  matched[(size_t)b * A + a] = (bestv < 0.45f) ? -1 : bestg;
  __syncthreads();
  if (threadIdx.x < G) {
    ull p = best[threadIdx.x];
    if (p) atomicMax(&gtpack[b * G + threadIdx.x], p);
  }
}

// ---------------- force match (separate dispatch = free coherence) ----------------
__global__ void force_kernel(const ull* __restrict__ gtpack, int* __restrict__ matched) {
  int b = blockIdx.x * blockDim.x + threadIdx.x;
  if (b < B) {
    for (int g = 0; g < G; ++g) {   // ascending g: last-wins tie order
      unsigned a = ~(unsigned)(gtpack[b * G + g] & 0xFFFFFFFFull);
      matched[(size_t)b * A + a] = g;
    }
  }
}

// ---------------- fused softmax + decode + giou (counted-vmcnt pipeline) ----------------
// Round-5 version, unchanged (counted vmcnt was neutral vs round-3 but not
// worse; keeping it). APB=64/NT=8, 2x23.3 KB LDS dbuf, DMA staging via
// __builtin_amdgcn_global_load_lds width=16.
#define APB 64
#define NT 8
#define NF4 (APB * C / 4)               // 1456 float4 per tile
#define NSTG 6                          // ceil(1456/256)
#define TAILN (NF4 - (NSTG - 1) * 256)  // 176

__device__ __forceinline__ void stage_tile(const float4* src, float* dst, int tid) {
  int wbase = tid & ~63;  // wave-uniform LDS base; HW adds lane*16
#pragma unroll
  for (int r = 0; r < NSTG - 1; ++r)
    __builtin_amdgcn_global_load_lds(
        (const __attribute__((address_space(1))) void*)(src + r * 256 + tid),
        (__attribute__((address_space(3))) void*)(dst + (r * 256 + wbase) * 4),
        16, 0, 0);
  if (tid < TAILN)   // waves issue {6,6,6,5} loads -> vmcnt(5) is the safe count
    __builtin_amdgcn_global_load_lds(
        (const __attribute__((address_space(1))) void*)(src + (NSTG - 1) * 256 + tid),
        (__attribute__((address_space(3))) void*)(dst + ((NSTG - 1) * 256 + wbase) * 4),
        16, 0, 0);
}

__global__ __launch_bounds__(256) void loss_kernel(
    const float4* __restrict__ logit4, const float4* __restrict__ reg,
    const float4* __restrict__ anchors, const float4* __restrict__ gt_boxes,
    const int* __restrict__ gt_labels, const int* __restrict__ matched,
    unsigned* __restrict__ cls_bits, int* __restrict__ num_fg, double* __restrict__ acc) {
  __shared__ float buf[2][APB * C];  // 2 x 23296 B -> 3 blocks/CU
  __shared__ double rb[4], rf[4];
  __shared__ int rc[4];
  int tid = threadIdx.x;
  int b = blockIdx.y;
  int tile0 = blockIdx.x * NT;
  size_t bbase4 = (size_t)b * A * C / 4;
  int t4 = tid >> 2, q = tid & 3;

  // ---- metadata prologue (before any DMA, so its waits are free) ----
  int mm[NT], tcls[NT];
#pragma unroll
  for (int t = 0; t < NT; ++t) {
    mm[t] = matched[(size_t)b * A + (tile0 + t) * APB + t4];
    tcls[t] = (mm[t] >= 0) ? gt_labels[b * G + mm[t]] : (C - 1);
  }

  // ---- prime the pipeline: 2 tiles in flight ----
  stage_tile(logit4 + bbase4 + (size_t)tile0 * NF4, buf[0], tid);
  stage_tile(logit4 + bbase4 + (size_t)(tile0 + 1) * NF4, buf[1], tid);

  double bbs = 0.0, fgs = 0.0;
  int cnt = 0;

#pragma unroll
  for (int t = 0; t < NT; ++t) {
    // wait: tile t's loads complete; stage(t+1)'s >=5 stay in flight
    if (t < NT - 1) {
      asm volatile("s_waitcnt vmcnt(5)" ::: "memory");
    } else {
      asm volatile("s_waitcnt vmcnt(0)" ::: "memory");
    }
    __builtin_amdgcn_s_barrier();          // all waves' tile-t chunks landed
    __builtin_amdgcn_sched_barrier(0);
    {
      const float* BC = buf[t & 1];
      int a = (tile0 + t) * APB + t4;
      const float* row = BC + t4 * C + 23 * q;
      const int cn = (q < 3) ? 23 : 22;
      float s0 = 0.f, s1 = 0.f, s2 = 0.f, s3 = 0.f;
      int j = 0;
#pragma unroll
      for (; j + 4 <= 20; j += 4) {
        s0 += __expf(row[j]);
        s1 += __expf(row[j + 1]);
        s2 += __expf(row[j + 2]);
        s3 += __expf(row[j + 3]);
      }
      for (; j < cn; ++j) s0 += __expf(row[j]);
      float s = (s0 + s1) + (s2 + s3);
      s += __shfl_xor(s, 1);
      s += __shfl_xor(s, 2);
      float lse = __logf(s);
      float xt = BC[t4 * C + tcls[t]];
      float loss = lse - xt;
      if (q == 0) {
        cls_bits[(size_t)b * A + a] = (mm[t] >= 0) ? 0u : __float_as_uint(loss);
        if (mm[t] >= 0) {
          fgs += (double)loss;
          cnt++;
          float4 an = anchors[(size_t)b * A + a];
          float4 rg = reg[(size_t)b * A + a];
          float4 gb = gt_boxes[b * G + mm[t]];
          float w = an.z - an.x, h = an.w - an.y;
          float cx = an.x + 0.5f * w, cy = an.y + 0.5f * h;
          float dw = fminf(rg.z, 4.135166556742356f);
          float dh = fminf(rg.w, 4.135166556742356f);
          float pcx = rg.x * w + cx, pcy = rg.y * h + cy;
          float pw = expf(dw) * w, ph = expf(dh) * h;
          float px0 = pcx - 0.5f * pw, py0 = pcy - 0.5f * ph;
          float px1 = pcx + 0.5f * pw, py1 = pcy + 0.5f * ph;
          float tlx = fmaxf(px0, gb.x), tly = fmaxf(py0, gb.y);
          float brx = fminf(px1, gb.z), bry = fminf(py1, gb.w);
          float iw = fmaxf(brx - tlx, 0.f), ih = fmaxf(bry - tly, 0.f);
          float inter = iw * ih;
          float ap = (px1 - px0) * (py1 - py0);
          float ag = (gb.z - gb.x) * (gb.w - gb.y);
          float uni = ap + ag - inter + 1e-16f;
          float iou = inter / uni;
          float ctlx = fminf(px0, gb.x), ctly = fminf(py0, gb.y);
          float cbrx = fmaxf(px1, gb.z), cbry = fmaxf(py1, gb.w);
          float acr = (cbrx - ctlx) * (cbry - ctly);
          float giou = iou - (acr - uni) / fmaxf(acr, 1e-16f);
          giou = fminf(fmaxf(giou, -1.f), 1.f);
          bbs += (double)(1.f - giou);
        }
      }
    }
    __builtin_amdgcn_s_barrier();          // all waves done reading buf[t&1]
    __builtin_amdgcn_sched_barrier(0);
    if (t + 2 < NT)                        // refill the buffer just freed
      stage_tile(logit4 + bbase4 + (size_t)(tile0 + t + 2) * NF4, buf[t & 1], tid);
  }

  int lane = tid & 63, wave = tid >> 6;
  for (int o = 32; o; o >>= 1) {
    bbs += __shfl_xor(bbs, o);
    fgs += __shfl_xor(fgs, o);
    cnt += __shfl_xor(cnt, o);
  }
  if (lane == 0) { rb[wave] = bbs; rf[wave] = fgs; rc[wave] = cnt; }
  __syncthreads();
  if (tid == 0) {
    double tb = rb[0] + rb[1] + rb[2] + rb[3];
    double tf = rf[0] + rf[1] + rf[2] + rf[3];
    int tc = rc[0] + rc[1] + rc[2] + rc[3];
    if (tb != 0.0) atomicAdd(&acc[0], tb);
    if (tf != 0.0) atomicAdd(&acc[1], tf);
    if (tc) atomicAdd(&num_fg[b], tc);
  }
}

// ---------------- fused 3-level radix select + bgsum + finalize ----------------
// One block per image b, 1024 threads. Each thread register-caches its 32
// packed loss words (fg anchors carry sentinel 0u = +0.0f: sentinel sits in
// bin 0 / value 0.0, which can only influence the result when T==0.0, where
// its r*T and v>T contributions are both exactly 0 -> bit-exact vs separate
// matched test). All histograms live in LDS; selection logic is verbatim
// the original select_kernel. Last block (device ticket) finalizes out[].
// The ticket here is cheap: only B=32 blocks pay the fence, not 4096.
__global__ __launch_bounds__(1024) void select_fused(
    const unsigned* __restrict__ bits, const int* __restrict__ num_fg,
    double* __restrict__ acc, int* __restrict__ ticket, float* __restrict__ out) {
  int b = blockIdx.x, tid = threadIdx.x;
  __shared__ int h[NBINS];
  __shared__ int gsum[256];
  __shared__ float sT;
  __shared__ int sDone, sKrem, sR;
  __shared__ unsigned sPref;
  __shared__ double sd[16];

  unsigned bv[32];
#pragma unroll
  for (int i = 0; i < 32; ++i) bv[i] = bits[(size_t)b * A + i * 1024 + tid];
  if (tid == 0) { sDone = 0; sR = 0; }

  // ---- level 1 ----
  for (int i = tid; i < NBINS; i += 1024) h[i] = 0;
  __syncthreads();
#pragma unroll
  for (int i = 0; i < 32; ++i) atomicAdd(&h[bv[i] >> 21], 1);
  __syncthreads();
  if (tid < 256) {
    int gs = 0;
#pragma unroll
    for (int j = 0; j < 8; ++j) gs += h[tid * 8 + j];
    gsum[tid] = gs;
  }
  __syncthreads();
  if (tid == 0) {
    int nf = num_fg[b];
    int k = 3 * nf;
    int bgcnt = A - nf;
    if (k <= 0) { sT = __builtin_inff(); sDone = 1; }
    else if (k >= bgcnt) { sT = -1.0f; sDone = 1; }
    else {
      int run = 0, gidx = 255;
      for (; gidx >= 0; --gidx) { if (run + gsum[gidx] >= k) break; run += gsum[gidx]; }
      if (gidx < 0) { sT = -1.0f; sDone = 1; }
      else {
        int bin = gidx * 8 + 7;
        for (; bin > gidx * 8; --bin) { if (run + h[bin] >= k) break; run += h[bin]; }
        sPref = (unsigned)bin; sKrem = k - run;
      }
    }
  }
  __syncthreads();

  if (!sDone) {  // block-uniform branch
    // ---- level 2 ----
    unsigned p1 = sPref;
    int k = sKrem;
    __syncthreads();
    for (int i = tid; i < NBINS; i += 1024) h[i] = 0;
    __syncthreads();
#pragma unroll
    for (int i = 0; i < 32; ++i)
      if ((bv[i] >> 21) == p1) atomicAdd(&h[(bv[i] >> 10) & 2047], 1);
    __syncthreads();
    if (tid < 256) {
      int gs = 0;
#pragma unroll
      for (int j = 0; j < 8; ++j) gs += h[tid * 8 + j];
      gsum[tid] = gs;
    }
    __syncthreads();
    if (tid == 0) {
      int run = 0, gidx = 255;
      for (; gidx >= 0; --gidx) { if (run + gsum[gidx] >= k) break; run += gsum[gidx]; }
      if (gidx < 0) { sT = -1.0f; sDone = 1; }
      else {
        int bin = gidx * 8 + 7;
        for (; bin > gidx * 8; --bin) { if (run + h[bin] >= k) break; run += h[bin]; }
        sPref = (p1 << 11) | (unsigned)bin; sKrem = k - run;
      }
    }
    __syncthreads();
  }
  if (!sDone) {
    // ---- level 3 ----
    unsigned p2 = sPref;
    int k = sKrem;
    __syncthreads();
    if (tid < 1024) h[tid] = 0;
    __syncthreads();
#pragma unroll
    for (int i = 0; i < 32; ++i)
      if ((bv[i] >> 10) == p2) atomicAdd(&h[bv[i] & 1023], 1);
    __syncthreads();
    if (tid < 256) {
      int gs = 0;
#pragma unroll
      for (int j = 0; j < 4; ++j) gs += h[tid * 4 + j];
      gsum[tid] = gs;
    }
    __syncthreads();
    if (tid == 0) {
      int run = 0, gidx = 255;
      for (; gidx >= 0; --gidx) { if (run + gsum[gidx] >= k) break; run += gsum[gidx]; }
      if (gidx < 0) { sT = -1.0f; }
      else {
        int bin = gidx * 4 + 3;
        for (; bin > gidx * 4; --bin) { if (run + h[bin] >= k) break; run += h[bin]; }
        sT = __uint_as_float((p2 << 10) | (unsigned)bin);
        sR = k - run;
      }
    }
    __syncthreads();
  }

  // ---- bg sum over threshold (+ r*T) ----
  float T = sT;
  float ls = 0.f;
#pragma unroll
  for (int i = 0; i < 32; ++i) {
    float v = __uint_as_float(bv[i]);
    if (v > T) ls += v;   // sentinel 0.0 adds exactly 0 when T<0
  }
  for (int o = 32; o; o >>= 1) ls += __shfl_xor(ls, o);
  if ((tid & 63) == 0) sd[tid >> 6] = (double)ls;
  __syncthreads();
  if (tid == 0) {
    double tt = 0.0;
    for (int w = 0; w < 16; ++w) tt += sd[w];
    if (sR > 0) tt += (double)sR * (double)sT;
    if (tt != 0.0) atomicAdd(&acc[2], tt);
    __threadfence();
    if (atomicAdd(ticket, 1) == B - 1) {
      // last block: finalize. acc[0..1]/num_fg written in a previous
      // dispatch (visible); acc[2] written by sibling blocks -> atomic read.
      int tot = 0;
      for (int bb = 0; bb < B; ++bb) tot += num_fg[bb];
      double N = (double)(tot > 1 ? tot : 1);
      double a2 = atomicAdd(&acc[2], 0.0);
      out[0] = (float)(2.0 * acc[0] / N);
      out[1] = (float)((acc[1] + a2) / N);
    }
  }
}

extern "C" void kernel_launch(void* const* d_in, const int* in_sizes, int n_in,
                              void* d_out, int out_size, void* d_ws, size_t ws_size,
                              hipStream_t stream) {
  const float4* logit4  = (const float4*)d_in[0];
  const float4* reg     = (const float4*)d_in[1];
  const float4* anchors = (const float4*)d_in[2];
  const float4* gtb     = (const float4*)d_in[3];
  const int*    gtl     = (const int*)d_in[4];

  char* ws = (char*)d_ws;
  int*      matched = (int*)(ws + offMatched);
  unsigned* cbits   = (unsigned*)(ws + offBits);
  int*      numfg   = (int*)(ws + offNumFg);
  double*   acc     = (double*)(ws + offAcc);
  int*      tick    = (int*)(ws + offTick);
  ull*      gtpack  = (ull*)(ws + offGt);
  float*    out     = (float*)d_out;

  init_kernel<<<8, 256, 0, stream>>>((int*)(ws + offNumFg), gtpack);
  match_kernel<<<dim3(A / 256, B), 256, 0, stream>>>(anchors, gtb, matched, gtpack);
  force_kernel<<<1, 64, 0, stream>>>(gtpack, matched);
  loss_kernel<<<dim3(A / (APB * NT), B), 256, 0, stream>>>(
      logit4, reg, anchors, gtb, gtl, matched, cbits, numfg, acc);
  select_fused<<<B, 1024, 0, stream>>>(cbits, numfg, acc, tick + 1, out);
}

// Round 7
// 627.309 us; speedup vs baseline: 1.2092x; 1.1246x over previous
//
#include <hip/hip_runtime.h>
#include <hip/hip_bf16.h>

#define B 32
#define A 32768
#define G 64
#define C 91
#define NBINS 2048

typedef unsigned long long ull;

// ---------------- workspace layout (bytes) ----------------
static constexpr size_t offMatched = 0;                     // B*A*4 (pre-force)
static constexpr size_t offBits    = (size_t)B * A * 4;     // packed loss bits
static constexpr size_t offNumFg   = (size_t)2 * B * A * 4; // B*4
static constexpr size_t offAcc     = offNumFg + B * 4;      // 3 doubles
static constexpr size_t offTick    = offAcc + 3 * 8;        // 2 ints
static constexpr size_t offGt      = offTick + 8;           // B*G ull (8-aligned)
static constexpr int    ZERO_N     = (int)((offGt - offNumFg) / 4);  // 40

// ---------------- init ----------------
__global__ void init_kernel(int* zero_base, ull* gtpack) {
  int i = blockIdx.x * 256 + threadIdx.x;
  if (i < ZERO_N) zero_base[i] = 0;
  if (i < B * G) gtpack[i] = 0xFFFFFFFFull;  // == (iou 0, anchor 0): argmax-of-zeros = 0
}

// ---------------- shared exact-arith helpers ----------------
// contract(off) pins identical codegen in BOTH kernels that use them, so the
// fixup's subtract-old / add-new is bit-exact vs what fused_loss accumulated.
__device__ __forceinline__ float giou_term(float4 an, float4 rg, float4 gb) {
#pragma clang fp contract(off)
  float w = an.z - an.x, h = an.w - an.y;
  float cx = an.x + 0.5f * w, cy = an.y + 0.5f * h;
  float dw = fminf(rg.z, 4.135166556742356f);
  float dh = fminf(rg.w, 4.135166556742356f);
  float pcx = rg.x * w + cx, pcy = rg.y * h + cy;
  float pw = expf(dw) * w, ph = expf(dh) * h;
  float px0 = pcx - 0.5f * pw, py0 = pcy - 0.5f * ph;
  float px1 = pcx + 0.5f * pw, py1 = pcy + 0.5f * ph;
  float tlx = fmaxf(px0, gb.x), tly = fmaxf(py0, gb.y);
  float brx = fminf(px1, gb.z), bry = fminf(py1, gb.w);
  float iw = fmaxf(brx - tlx, 0.f), ih = fmaxf(bry - tly, 0.f);
  float inter = iw * ih;
  float ap = (px1 - px0) * (py1 - py0);
  float ag = (gb.z - gb.x) * (gb.w - gb.y);
  float uni = ap + ag - inter + 1e-16f;
  float iou = inter / uni;
  float ctlx = fminf(px0, gb.x), ctly = fminf(py0, gb.y);
  float cbrx = fmaxf(px1, gb.z), cbry = fmaxf(py1, gb.w);
  float acr = (cbrx - ctlx) * (cbry - ctly);
  float giou = iou - (acr - uni) / fmaxf(acr, 1e-16f);
  giou = fminf(fmaxf(giou, -1.f), 1.f);
  return 1.f - giou;
}

// Serial replay of fused_loss's 4-lane-split lse, bit-exact: lane q sums
// s0:{0,4,8,12,16,20,21,22(q<3)} s1:{1,5,9,13,17} s2:{2,..} s3:{3,..} over its
// 23/22 slice, partial (s0+s1)+(s2+s3); cross-lane shfl gives
// (sq0+sq1)+(sq2+sq3) (f32 + is commutative -> lane order irrelevant).
__device__ __forceinline__ float lse_replay(const float* row) {
#pragma clang fp contract(off)
  float sq[4];
#pragma unroll
  for (int q = 0; q < 4; ++q) {
    const float* r = row + 23 * q;
    const int cn = (q < 3) ? 23 : 22;
    float s0 = 0.f, s1 = 0.f, s2 = 0.f, s3 = 0.f;
    int j = 0;
    for (; j + 4 <= 20; j += 4) {
      s0 += __expf(r[j]);
      s1 += __expf(r[j + 1]);
      s2 += __expf(r[j + 2]);
      s3 += __expf(r[j + 3]);
    }
    for (; j < cn; ++j) s0 += __expf(r[j]);
    sq[q] = (s0 + s1) + (s2 + s3);
  }
  return __logf((sq[0] + sq[1]) + (sq[2] + sq[3]));
}

// ---------------- inline per-anchor match (bit-identical to old match_kernel) ----
// q-lane handles GTs [16q,16q+16); strict-greater keeps first max within the
// range; cross-q u64 reduce packs (iou_bits, G-1-g) so ties pick smallest g
// == jnp.argmax first-occurrence. gtpack candidates (iou>0) filtered by the
// u32 hi-word (stale-safe, monotone) into block-local LDS bestl[].
__device__ __forceinline__ void inline_match(
    const float4* __restrict__ anchors_b, const float4* gtb, const float* gtarea,
    ull* bestl, const int* __restrict__ gtl_b, int aidx, int q, int& mm, int& tcl) {
#pragma clang fp contract(off)
  float4 an = anchors_b[aidx];
  float area_a = (an.z - an.x) * (an.w - an.y);
  const unsigned lo = ~(unsigned)aidx;
  const unsigned* besthi = (const unsigned*)bestl;  // little-endian: hi at [2g+1]
  float bestv = -1.0f;
  int bestg = 0;
  const int g0 = q * 16;
#pragma unroll 4
  for (int g = g0; g < g0 + 16; ++g) {
    float4 gb = gtb[g];
    float tlx = fmaxf(gb.x, an.x), tly = fmaxf(gb.y, an.y);
    float brx = fminf(gb.z, an.z), bry = fminf(gb.w, an.w);
    float w = fmaxf(brx - tlx, 0.0f), h = fmaxf(bry - tly, 0.0f);
    float inter = w * h;
    float iou = 0.0f;
    if (inter > 0.0f) {
      iou = inter / (gtarea[g] + area_a - inter + 1e-16f);
      unsigned ib = __float_as_uint(iou);
      if (ib >= besthi[2 * g + 1]) atomicMax(&bestl[g], ((ull)ib << 32) | lo);
    }
    if (iou > bestv) { bestv = iou; bestg = g; }
  }
  // bestv >= 0 after loop (iou=0 > -1 on first iter) -> unsigned-safe pack
  ull p = ((ull)__float_as_uint(bestv) << 32) | (unsigned)(G - 1 - bestg);
  ull p1 = __shfl_xor(p, 1); p = (p > p1) ? p : p1;
  ull p2 = __shfl_xor(p, 2); p = (p > p2) ? p : p2;
  float bv = __uint_as_float((unsigned)(p >> 32));
  mm = (bv < 0.45f) ? -1 : (G - 1 - (int)(p & 0xFFFFFFFFull));
  tcl = (mm >= 0) ? gtl_b[mm] : (C - 1);
}

// ---------------- fused match + softmax + decode + giou ----------------
// Block = 256 threads owns NT=8 x 64-anchor tiles. Per iteration t:
//   stage(t+1) DMA  ->  inline match(t+1) [VALU, overlaps DMA latency]
//   -> loss(t) from LDS -> __syncthreads() (vmcnt drain = DMA handshake).
// The previously-separate match_kernel (~120 us, VALU/latency-bound) now
// executes entirely under the logits stream. gtpack via block LDS -> one
// global atomicMax per GT per block (device scope, coherent across XCDs).
#define APB 64
#define NT 8
#define NF4 (APB * C / 4)               // 1456 float4 per tile
#define NSTG 6                          // ceil(1456/256)
#define TAILN (NF4 - (NSTG - 1) * 256)  // 176

__device__ __forceinline__ void stage_tile(const float4* src, float* dst, int tid) {
  int wbase = tid & ~63;  // wave-uniform LDS base; HW adds lane*16
#pragma unroll
  for (int r = 0; r < NSTG - 1; ++r)
    __builtin_amdgcn_global_load_lds(
        (const __attribute__((address_space(1))) void*)(src + r * 256 + tid),
        (__attribute__((address_space(3))) void*)(dst + (r * 256 + wbase) * 4),
        16, 0, 0);
  if (tid < TAILN)
    __builtin_amdgcn_global_load_lds(
        (const __attribute__((address_space(1))) void*)(src + (NSTG - 1) * 256 + tid),
        (__attribute__((address_space(3))) void*)(dst + ((NSTG - 1) * 256 + wbase) * 4),
        16, 0, 0);
}

__global__ __launch_bounds__(256) void fused_loss_kernel(
    const float4* __restrict__ logit4, const float4* __restrict__ reg,
    const float4* __restrict__ anchors, const float4* __restrict__ gt_boxes,
    const int* __restrict__ gt_labels, int* __restrict__ matched,
    unsigned* __restrict__ cls_bits, int* __restrict__ num_fg,
    double* __restrict__ acc, ull* __restrict__ gtpack) {
  __shared__ float buf[2][APB * C];  // 2 x 23296 B
  __shared__ float4 gtb[G];
  __shared__ float gtarea[G];
  __shared__ ull bestl[G];
  __shared__ double rb[4], rf[4];
  __shared__ int rc[4];
  int tid = threadIdx.x;
  int b = blockIdx.y;
  int tile0 = blockIdx.x * NT;
  size_t bbase4 = (size_t)b * A * C / 4;
  size_t abase = (size_t)b * A;
  const float4* anchors_b = anchors + abase;
  const int* gtl_b = gt_labels + b * G;
  int t4 = tid >> 2, q = tid & 3;

  if (tid < G) {
    float4 g = gt_boxes[b * G + tid];
    gtb[tid] = g;
    gtarea[tid] = (g.z - g.x) * (g.w - g.y);
    bestl[tid] = 0ull;
  }
  stage_tile(logit4 + bbase4 + (size_t)tile0 * NF4, buf[0], tid);
  __syncthreads();  // gt LDS ready; vmcnt(0) drain -> buf[0] ready

  int mm, tcl;
  inline_match(anchors_b, gtb, gtarea, bestl, gtl_b, tile0 * APB + t4, q, mm, tcl);

  double bbs = 0.0, fgs = 0.0;
  int cnt = 0;

  for (int t = 0; t < NT; ++t) {
    if (t + 1 < NT)
      stage_tile(logit4 + bbase4 + (size_t)(tile0 + t + 1) * NF4, buf[(t + 1) & 1], tid);
    int mmN = 0, tclN = 0;
    if (t + 1 < NT)  // match for NEXT tile: VALU work under the DMA in flight
      inline_match(anchors_b, gtb, gtarea, bestl, gtl_b,
                   (tile0 + t + 1) * APB + t4, q, mmN, tclN);
    {
      const float* BC = buf[t & 1];
      int a = (tile0 + t) * APB + t4;
      const float* row = BC + t4 * C + 23 * q;
      const int cn = (q < 3) ? 23 : 22;
      float s0 = 0.f, s1 = 0.f, s2 = 0.f, s3 = 0.f;
      int j = 0;
#pragma unroll
      for (; j + 4 <= 20; j += 4) {
        s0 += __expf(row[j]);
        s1 += __expf(row[j + 1]);
        s2 += __expf(row[j + 2]);
        s3 += __expf(row[j + 3]);
      }
      for (; j < cn; ++j) s0 += __expf(row[j]);
      float s = (s0 + s1) + (s2 + s3);
      s += __shfl_xor(s, 1);
      s += __shfl_xor(s, 2);
      float lse = __logf(s);
      float xt = BC[t4 * C + tcl];
      float loss = lse - xt;
      if (q == 0) {
        matched[abase + a] = mm;  // pre-force; fixup_kernel reads it
        cls_bits[abase + a] = (mm >= 0) ? 0u : __float_as_uint(loss);
        if (mm >= 0) {
          fgs += (double)loss;
          cnt++;
          float4 an = anchors_b[a];
          float4 rg = reg[abase + a];
          bbs += (double)giou_term(an, rg, gtb[mm]);
        }
      }
    }
    mm = mmN;
    tcl = tclN;
    __syncthreads();  // buf[t&1] free; vmcnt(0) drain readies buf[(t+1)&1]
  }

  // flush block-local gtpack candidates (device-scope atomic, cross-XCD safe)
  if (tid < G) {
    ull p = bestl[tid];
    if (p) atomicMax(&gtpack[b * G + tid], p);
  }

  int lane = tid & 63, wave = tid >> 6;
  for (int o = 32; o; o >>= 1) {
    bbs += __shfl_xor(bbs, o);
    fgs += __shfl_xor(fgs, o);
    cnt += __shfl_xor(cnt, o);
  }
  if (lane == 0) { rb[wave] = bbs; rf[wave] = fgs; rc[wave] = cnt; }
  __syncthreads();
  if (tid == 0) {
    double tb = rb[0] + rb[1] + rb[2] + rb[3];
    double tf = rf[0] + rf[1] + rf[2] + rf[3];
    int tc = rc[0] + rc[1] + rc[2] + rc[3];
    if (tb != 0.0) atomicAdd(&acc[0], tb);
    if (tf != 0.0) atomicAdd(&acc[1], tf);
    if (tc) atomicAdd(&num_fg[b], tc);
  }
}

// ---------------- force + fixup (separate dispatch = free coherence) ----------------
// One block per image, 64 threads (one wave), thread = g. Last-wins dedup of
// forced anchors, then each winner repairs its anchor's contributions:
// subtract old fg terms (bit-exact replay) / zero the bg cls_bits, add new fg
// terms with gt g, adjust num_fg. <=64 anchors/image -> ~5 us total.
__global__ __launch_bounds__(64) void fixup_kernel(
    const float* __restrict__ logits, const float4* __restrict__ reg,
    const float4* __restrict__ anchors, const float4* __restrict__ gt_boxes,
    const int* __restrict__ gt_labels, const ull* __restrict__ gtpack,
    const int* __restrict__ matched, unsigned* __restrict__ cls_bits,
    int* __restrict__ num_fg, double* __restrict__ acc) {
  int b = blockIdx.x, g = threadIdx.x;
  __shared__ unsigned aArr[G];
  unsigned a = ~(unsigned)(gtpack[b * G + g] & 0xFFFFFFFFull);
  aArr[g] = a;
  __syncthreads();
  bool winner = true;
  for (int g2 = g + 1; g2 < G; ++g2)
    if (aArr[g2] == a) { winner = false; break; }  // last-wins tie order

  double d_bb = 0.0, d_fg = 0.0;
  int d_cnt = 0;
  int m_old = matched[(size_t)b * A + a];
  if (winner && m_old != g) {
    const float* row = logits + ((size_t)b * A + a) * C;
    float lse = lse_replay(row);
    float4 an = anchors[(size_t)b * A + a];
    float4 rg = reg[(size_t)b * A + a];
    if (m_old >= 0) {  // was fg with other gt: subtract old terms
      d_fg -= (double)(lse - row[gt_labels[b * G + m_old]]);
      d_bb -= (double)giou_term(an, rg, gt_boxes[b * G + m_old]);
    } else {           // was bg: remove from hard-negative pool, count new fg
      cls_bits[(size_t)b * A + a] = 0u;
      d_cnt = 1;
    }
    d_fg += (double)(lse - row[gt_labels[b * G + g]]);
    d_bb += (double)giou_term(an, rg, gt_boxes[b * G + g]);
  }
  for (int o = 32; o; o >>= 1) {
    d_bb += __shfl_xor(d_bb, o);
    d_fg += __shfl_xor(d_fg, o);
    d_cnt += __shfl_xor(d_cnt, o);
  }
  if (g == 0) {
    if (d_bb != 0.0) atomicAdd(&acc[0], d_bb);
    if (d_fg != 0.0) atomicAdd(&acc[1], d_fg);
    if (d_cnt) atomicAdd(&num_fg[b], d_cnt);
  }
}

// ---------------- fused 3-level radix select + bgsum + finalize ----------------
// One block per image b, 1024 threads. Each thread register-caches its 32
// packed loss words (fg anchors carry sentinel 0u = +0.0f: sentinel sits in
// bin 0 / value 0.0, which can only influence the result when T==0.0, where
// its r*T and v>T contributions are both exactly 0 -> bit-exact vs separate
// matched test). Ticket fence only across B=32 blocks (cheap).
__global__ __launch_bounds__(1024) void select_fused(
    const unsigned* __restrict__ bits, const int* __restrict__ num_fg,
    double* __restrict__ acc, int* __restrict__ ticket, float* __restrict__ out) {
  int b = blockIdx.x, tid = threadIdx.x;
  __shared__ int h[NBINS];
  __shared__ int gsum[256];
  __shared__ float sT;
  __shared__ int sDone, sKrem, sR;
  __shared__ unsigned sPref;
  __shared__ double sd[16];

  unsigned bv[32];
#pragma unroll
  for (int i = 0; i < 32; ++i) bv[i] = bits[(size_t)b * A + i * 1024 + tid];
  if (tid == 0) { sDone = 0; sR = 0; }

  // ---- level 1 ----
  for (int i = tid; i < NBINS; i += 1024) h[i] = 0;
  __syncthreads();
#pragma unroll
  for (int i = 0; i < 32; ++i) atomicAdd(&h[bv[i] >> 21], 1);
  __syncthreads();
  if (tid < 256) {
    int gs = 0;
#pragma unroll
    for (int j = 0; j < 8; ++j) gs += h[tid * 8 + j];
    gsum[tid] = gs;
  }
  __syncthreads();
  if (tid == 0) {
    int nf = num_fg[b];
    int k = 3 * nf;
    int bgcnt = A - nf;
    if (k <= 0) { sT = __builtin_inff(); sDone = 1; }
    else if (k >= bgcnt) { sT = -1.0f; sDone = 1; }
    else {
      int run = 0, gidx = 255;
      for (; gidx >= 0; --gidx) { if (run + gsum[gidx] >= k) break; run += gsum[gidx]; }
      if (gidx < 0) { sT = -1.0f; sDone = 1; }
      else {
        int bin = gidx * 8 + 7;
        for (; bin > gidx * 8; --bin) { if (run + h[bin] >= k) break; run += h[bin]; }
        sPref = (unsigned)bin; sKrem = k - run;
      }
    }
  }
  __syncthreads();

  if (!sDone) {  // block-uniform branch
    // ---- level 2 ----
    unsigned p1 = sPref;
    int k = sKrem;
    __syncthreads();
    for (int i = tid; i < NBINS; i += 1024) h[i] = 0;
    __syncthreads();
#pragma unroll
    for (int i = 0; i < 32; ++i)
      if ((bv[i] >> 21) == p1) atomicAdd(&h[(bv[i] >> 10) & 2047], 1);
    __syncthreads();
    if (tid < 256) {
      int gs = 0;
#pragma unroll
      for (int j = 0; j < 8; ++j) gs += h[tid * 8 + j];
      gsum[tid] = gs;
    }
    __syncthreads();
    if (tid == 0) {
      int run = 0, gidx = 255;
      for (; gidx >= 0; --gidx) { if (run + gsum[gidx] >= k) break; run += gsum[gidx]; }
      if (gidx < 0) { sT = -1.0f; sDone = 1; }
      else {
        int bin = gidx * 8 + 7;
        for (; bin > gidx * 8; --bin) { if (run + h[bin] >= k) break; run += h[bin]; }
        sPref = (p1 << 11) | (unsigned)bin; sKrem = k - run;
      }
    }
    __syncthreads();
  }
  if (!sDone) {
    // ---- level 3 ----
    unsigned p2 = sPref;
    int k = sKrem;
    __syncthreads();
    if (tid < 1024) h[tid] = 0;
    __syncthreads();
#pragma unroll
    for (int i = 0; i < 32; ++i)
      if ((bv[i] >> 10) == p2) atomicAdd(&h[bv[i] & 1023], 1);
    __syncthreads();
    if (tid < 256) {
      int gs = 0;
#pragma unroll
      for (int j = 0; j < 4; ++j) gs += h[tid * 4 + j];
      gsum[tid] = gs;
    }
    __syncthreads();
    if (tid == 0) {
      int run = 0, gidx = 255;
      for (; gidx >= 0; --gidx) { if (run + gsum[gidx] >= k) break; run += gsum[gidx]; }
      if (gidx < 0) { sT = -1.0f; }
      else {
        int bin = gidx * 4 + 3;
        for (; bin > gidx * 4; --bin) { if (run + h[bin] >= k) break; run += h[bin]; }
        sT = __uint_as_float((p2 << 10) | (unsigned)bin);
        sR = k - run;
      }
    }
    __syncthreads();
  }

  // ---- bg sum over threshold (+ r*T) ----
  float T = sT;
  float ls = 0.f;
#pragma unroll
  for (int i = 0; i < 32; ++i) {
    float v = __uint_as_float(bv[i]);
    if (v > T) ls += v;   // sentinel 0.0 adds exactly 0 when T<0
  }
  for (int o = 32; o; o >>= 1) ls += __shfl_xor(ls, o);
  if ((tid & 63) == 0) sd[tid >> 6] = (double)ls;
  __syncthreads();
  if (tid == 0) {
    double tt = 0.0;
    for (int w = 0; w < 16; ++w) tt += sd[w];
    if (sR > 0) tt += (double)sR * (double)sT;
    if (tt != 0.0) atomicAdd(&acc[2], tt);
    __threadfence();
    if (atomicAdd(ticket, 1) == B - 1) {
      int tot = 0;
      for (int bb = 0; bb < B; ++bb) tot += num_fg[bb];
      double N = (double)(tot > 1 ? tot : 1);
      double a2 = atomicAdd(&acc[2], 0.0);
      out[0] = (float)(2.0 * acc[0] / N);
      out[1] = (float)((acc[1] + a2) / N);
    }
  }
}

extern "C" void kernel_launch(void* const* d_in, const int* in_sizes, int n_in,
                              void* d_out, int out_size, void* d_ws, size_t ws_size,
                              hipStream_t stream) {
  const float4* logit4  = (const float4*)d_in[0];
  const float4* reg     = (const float4*)d_in[1];
  const float4* anchors = (const float4*)d_in[2];
  const float4* gtb     = (const float4*)d_in[3];
  const int*    gtl     = (const int*)d_in[4];

  char* ws = (char*)d_ws;
  int*      matched = (int*)(ws + offMatched);
  unsigned* cbits   = (unsigned*)(ws + offBits);
  int*      numfg   = (int*)(ws + offNumFg);
  double*   acc     = (double*)(ws + offAcc);
  int*      tick    = (int*)(ws + offTick);
  ull*      gtpack  = (ull*)(ws + offGt);
  float*    out     = (float*)d_out;

  init_kernel<<<8, 256, 0, stream>>>((int*)(ws + offNumFg), gtpack);
  fused_loss_kernel<<<dim3(A / (APB * NT), B), 256, 0, stream>>>(
      logit4, reg, anchors, gtb, gtl, matched, cbits, numfg, acc, gtpack);
  fixup_kernel<<<B, 64, 0, stream>>>(
      (const float*)d_in[0], reg, anchors, gtb, gtl, gtpack, matched, cbits, numfg, acc);
  select_fused<<<B, 1024, 0, stream>>>(cbits, numfg, acc, tick + 1, out);
}